// Round 10
// baseline (122.220 us; speedup 1.0000x reference)
//
#include <hip/hip_runtime.h>

// MHA forward, MI355X gfx950.
// Sizes: B=4, S=2048, DIN=EMB=1024, H=16, D(head)=64.
// Stage 0: one-shot fp32->bf16 convert of x and Wq/Wk/Wv.
// Stage 1: fused QKV GEMM: BM=256 BN=128 BK=64, 4 waves (wave tile 128x64 —
//          562 B LDS per MFMA vs 750 at 64x64), A double-buffered (stage at
//          iter top, full-iteration latency cover), B single-buffered
//          (staged under kk1 MFMA after mid-barrier), 2 barriers per 64
//          MFMA, XOR-chunk swizzle, LDS-bounce epilogue, V stored [b,h,d,s].
// Stage 2: causal flash attention, BQ=128 (8 waves), KVBLK=64, fixed-max
//          exp2 softmax, K/V^T gld16 dbuf, one barrier/tile (unchanged R9).

#define BSZ 4
#define SLEN 2048
#define DIN 1024
#define EMB 1024
#define HNO 16
#define HSZ 64

typedef unsigned short u16;
typedef __bf16 bf16x8_t __attribute__((ext_vector_type(8)));
typedef float f32x4_t __attribute__((ext_vector_type(4)));

__device__ __forceinline__ u16 f2bf(float f) {
    unsigned u = __float_as_uint(f);
    u += 0x7FFFu + ((u >> 16) & 1u);   // RNE; inputs are finite
    return (u16)(u >> 16);
}

__device__ __forceinline__ float exp2_fast(float x) {
    float r;
    asm("v_exp_f32 %0, %1" : "=v"(r) : "v"(x));
    return r;
}

__device__ __forceinline__ unsigned cvt_pk_bf16(float lo, float hi) {
    unsigned r;
    asm("v_cvt_pk_bf16_f32 %0, %1, %2" : "=v"(r) : "v"(lo), "v"(hi));
    return r;
}

__device__ __forceinline__ void gld16(void* lds, const void* g) {
    __builtin_amdgcn_global_load_lds(
        (const __attribute__((address_space(1))) void*)g,
        (__attribute__((address_space(3))) void*)lds, 16, 0, 0);
}

#define VMW0()                                                                 \
    do {                                                                       \
        asm volatile("s_waitcnt vmcnt(0)" ::: "memory");                       \
        __builtin_amdgcn_sched_barrier(0);                                     \
    } while (0)

#define LGKM0()                                                                \
    do {                                                                       \
        asm volatile("s_waitcnt lgkmcnt(0)" ::: "memory");                     \
        __builtin_amdgcn_sched_barrier(0);                                     \
    } while (0)

// ---------------------------------------------------------------------------
// Stage 0: fp32 -> bf16
// ---------------------------------------------------------------------------
__global__ __launch_bounds__(256) void cvt_bf16_kernel(
    const float* __restrict__ x,  const float* __restrict__ wq,
    const float* __restrict__ wk, const float* __restrict__ wv,
    u16* __restrict__ xo, u16* __restrict__ wo)
{
    const int y = blockIdx.y;
    const float* src = (y == 0) ? x : (y == 1) ? wq : (y == 2) ? wk : wv;
    u16* dst = (y == 0) ? xo : wo + (size_t)(y - 1) * (EMB * DIN);
    const int n8 = (y == 0) ? (BSZ * SLEN * DIN / 8) : (EMB * DIN / 8);

    for (int i = blockIdx.x * 256 + threadIdx.x; i < n8; i += gridDim.x * 256) {
        float4 a = *reinterpret_cast<const float4*>(src + (size_t)i * 8);
        float4 b = *reinterpret_cast<const float4*>(src + (size_t)i * 8 + 4);
        union { u16 h[8]; uint4 u; } p;
        p.h[0] = f2bf(a.x); p.h[1] = f2bf(a.y); p.h[2] = f2bf(a.z); p.h[3] = f2bf(a.w);
        p.h[4] = f2bf(b.x); p.h[5] = f2bf(b.y); p.h[6] = f2bf(b.z); p.h[7] = f2bf(b.w);
        *reinterpret_cast<uint4*>(dst + (size_t)i * 8) = p.u;
    }
}

// ---------------------------------------------------------------------------
// Stage 1: fused QKV GEMM. BM=256 BN=128 BK=64, 4 waves (2x2, wave 128x64).
// A dbuf 2x32KB + B 16KB = 80 KB -> 2 blocks/CU.
// grid = 768 (32 M x 24 N, 8x12-rect XCD-swizzled), block = 256.
// ---------------------------------------------------------------------------
__global__ __launch_bounds__(256, 2) void qkv_gemm_kernel(
    const u16* __restrict__ xb, const u16* __restrict__ wb,
    const float* __restrict__ bq, const float* __restrict__ bk,
    const float* __restrict__ bv,
    u16* __restrict__ qkv, u16* __restrict__ vt)
{
    __shared__ __attribute__((aligned(16))) u16 SH[2 * 16384 + 8192]; // 80 KB
    u16* Bs = SH + 2 * 16384;

    const int t    = threadIdx.x;
    const int wid  = t >> 6;
    const int lane = t & 63;
    const int g    = lane >> 4;
    const int r16  = lane & 15;
    const int wm   = wid >> 1, wn = wid & 1;

    // XCD swizzle: each XCD owns an 8M x 12N rectangle (96 blocks)
    const int wg  = blockIdx.x;
    const int xcd = wg & 7;
    const int j   = wg >> 3;             // 0..95
    const int jm  = j / 12;              // 0..7
    const int jn  = j - jm * 12;         // 0..11
    const int m0  = ((xcd & 3) * 8 + jm) * 256;
    const int n0g = ((xcd >> 2) * 12 + jn) * 128;

    // staging: thread t -> row (unit*32 + t>>3), chunk t&7, source pre-swz
    const int rowoff = t >> 3;                       // 0..31
    const int colswz = ((t & 7) ^ (rowoff & 7)) * 8;
    const u16* srcA = xb + (size_t)(m0 + rowoff) * DIN + colswz;
    const u16* srcB = wb + (size_t)(n0g + rowoff) * DIN + colswz;

    // read slot: phys chunk = (kk*4+g) ^ (r16&7)
    const int s0 = (g ^ (r16 & 7)) * 8;

    f32x4_t acc[8][4] = {};

    // ---- prologue: stage A(0) -> buf0, B(0) -> Bs
#pragma unroll
    for (int u = 0; u < 8; ++u)
        gld16(SH + u * 2048 + t * 8, srcA + (size_t)u * 32 * DIN);
#pragma unroll
    for (int v = 0; v < 4; ++v)
        gld16(Bs + v * 2048 + t * 8, srcB + (size_t)v * 32 * DIN);
    VMW0();
    __builtin_amdgcn_s_barrier();

#pragma unroll 1
    for (int kt = 0; kt < 16; ++kt) {
        const bool nl = (kt != 15);
        const u16* Acur = SH + (kt & 1) * 16384;
        u16*       Aalt = SH + ((kt + 1) & 1) * 16384;

        // 1. stage A(t+1) early — covered by the whole iteration
        if (nl) {
#pragma unroll
            for (int u = 0; u < 8; ++u)
                gld16(Aalt + u * 2048 + t * 8,
                      srcA + (size_t)u * 32 * DIN + (kt + 1) * 64);
        }

        // 2. read kk0 A-frags + both B-frag halves
        bf16x8_t af[8], bf0[4], bf1[4];
#pragma unroll
        for (int i2 = 0; i2 < 8; ++i2)
            af[i2] = *reinterpret_cast<const bf16x8_t*>(
                Acur + (wm * 128 + i2 * 16 + r16) * 64 + s0);
#pragma unroll
        for (int j2 = 0; j2 < 4; ++j2) {
            bf0[j2] = *reinterpret_cast<const bf16x8_t*>(
                Bs + (wn * 64 + j2 * 16 + r16) * 64 + s0);
            bf1[j2] = *reinterpret_cast<const bf16x8_t*>(
                Bs + (wn * 64 + j2 * 16 + r16) * 64 + (s0 ^ 32));
        }

        // 3. MFMA kk0
        __builtin_amdgcn_s_setprio(1);
#pragma unroll
        for (int i2 = 0; i2 < 8; ++i2)
#pragma unroll
            for (int j2 = 0; j2 < 4; ++j2)
                acc[i2][j2] = __builtin_amdgcn_mfma_f32_16x16x32_bf16(
                    af[i2], bf0[j2], acc[i2][j2], 0, 0, 0);
        __builtin_amdgcn_s_setprio(0);

        // 4. read kk1 A-frags (reuse regs)
#pragma unroll
        for (int i2 = 0; i2 < 8; ++i2)
            af[i2] = *reinterpret_cast<const bf16x8_t*>(
                Acur + (wm * 128 + i2 * 16 + r16) * 64 + (s0 ^ 32));

        // 5. all waves' B/A reads retired -> B buffer free
        LGKM0();
        __builtin_amdgcn_s_barrier();

        // 6. stage B(t+1) — covered by kk1 MFMA
        if (nl) {
#pragma unroll
            for (int v = 0; v < 4; ++v)
                gld16(Bs + v * 2048 + t * 8,
                      srcB + (size_t)v * 32 * DIN + (kt + 1) * 64);
        }

        // 7. MFMA kk1
        __builtin_amdgcn_s_setprio(1);
#pragma unroll
        for (int i2 = 0; i2 < 8; ++i2)
#pragma unroll
            for (int j2 = 0; j2 < 4; ++j2)
                acc[i2][j2] = __builtin_amdgcn_mfma_f32_16x16x32_bf16(
                    af[i2], bf1[j2], acc[i2][j2], 0, 0, 0);
        __builtin_amdgcn_s_setprio(0);

        // 8. next tiles staged & visible
        VMW0();
        __builtin_amdgcn_s_barrier();
    }

    // ---- epilogue: per 128-row half, acc -> LDS bounce -> coalesced stores
    const size_t per = (size_t)BSZ * HNO * SLEN * HSZ;
    const bool isV = (n0g >= 2 * 1024);
    u16* lout = SH;                       // [128][136] u16 = 34.8 KB
    const int b  = m0 >> 11;              // block-uniform (256 | 2048)
    const int sB = m0 & 2047;
    const int mat = n0g >> 10;            // block-uniform (128 | 1024)

#pragma unroll
    for (int h = 0; h < 2; ++h) {
        __syncthreads();
        if (!isV) {
            if (wm == h) {
#pragma unroll
                for (int j2 = 0; j2 < 4; ++j2) {
                    const int el = wn * 64 + j2 * 16 + r16;
                    const int e  = (n0g + el) & 1023;
                    const float bval = (mat == 0) ? bq[e] : bk[e];
                    const float qsv  = (mat == 0) ? 0.125f * 1.44269504f : 1.0f;
#pragma unroll
                    for (int i2 = 0; i2 < 8; ++i2)
#pragma unroll
                        for (int r = 0; r < 4; ++r) {
                            int ml = i2 * 16 + g * 4 + r;
                            lout[ml * 136 + el] =
                                f2bf((acc[i2][j2][r] + bval) * qsv);
                        }
                }
            }
            __syncthreads();
#pragma unroll
            for (int it = 0; it < 8; ++it) {
                int cid = it * 256 + t;          // 128 rows x 16 chunks
                int row = cid >> 4;
                int cc  = cid & 15;
                int e   = (n0g + cc * 8) & 1023;
                int s   = sB + h * 128 + row;
                uint4 v = *reinterpret_cast<const uint4*>(&lout[row * 136 + cc * 8]);
                *reinterpret_cast<uint4*>(qkv + (size_t)mat * per +
                    ((((size_t)b * HNO) + (e >> 6)) * SLEN + s) * HSZ + (e & 63)) = v;
            }
        } else {
            // V: transposed bounce lout_T[el][ml], packed uint2 writes
            if (wm == h) {
#pragma unroll
                for (int j2 = 0; j2 < 4; ++j2) {
                    const int el = wn * 64 + j2 * 16 + r16;
                    const int e  = (n0g + el) & 1023;
                    const float bval = bv[e];
#pragma unroll
                    for (int i2 = 0; i2 < 8; ++i2) {
                        uint2 pk;
                        pk.x = cvt_pk_bf16(acc[i2][j2][0] + bval,
                                           acc[i2][j2][1] + bval);
                        pk.y = cvt_pk_bf16(acc[i2][j2][2] + bval,
                                           acc[i2][j2][3] + bval);
                        *reinterpret_cast<uint2*>(
                            &lout[el * 136 + i2 * 16 + g * 4]) = pk;
                    }
                }
            }
            __syncthreads();
#pragma unroll
            for (int it = 0; it < 8; ++it) {
                int cid = it * 256 + t;          // 128 els x 16 s-chunks
                int el  = cid >> 4;
                int sc  = cid & 15;
                int egl = n0g + el;
                int hh  = (egl >> 6) & 15;
                int d   = egl & 63;
                int s   = sB + h * 128 + sc * 8;
                uint4 v = *reinterpret_cast<const uint4*>(&lout[el * 136 + sc * 8]);
                *reinterpret_cast<uint4*>(vt +
                    (((size_t)(b * HNO + hh)) * HSZ + d) * SLEN + s) = v;
            }
        }
    }
}

// ---------------------------------------------------------------------------
// Stage 2: causal flash attention (unchanged from R9).
// ---------------------------------------------------------------------------
__global__ __launch_bounds__(512, 6) void attn_kernel(
    const u16* __restrict__ qb, const u16* __restrict__ kb,
    const u16* __restrict__ vtg, float* __restrict__ out)
{
    __shared__ __attribute__((aligned(16))) u16 Ks[2][64][64];
    __shared__ __attribute__((aligned(16))) u16 Vt[2][64][64];
    __shared__ __attribute__((aligned(16))) u16 P2[8][16][72];

    const int t    = threadIdx.x;
    const int wid  = t >> 6;
    const int lane = t & 63;
    const int g    = lane >> 4;
    const int r16  = lane & 15;
    const int r8   = r16 & 7;

    const int w   = blockIdx.x;
    const int idx = w >> 3;
    const int bh  = (w & 7) * 8 + (idx & 7);
    const int qt  = 15 - (idx >> 3);
    const int q0  = qt * 128;
    const size_t base = (size_t)bh * (SLEN * HSZ);

    const int qi = q0 + wid * 16 + r16;
    bf16x8_t qf0 = *reinterpret_cast<const bf16x8_t*>(&qb[base + (size_t)qi * HSZ + g * 8]);
    bf16x8_t qf1 = *reinterpret_cast<const bf16x8_t*>(&qb[base + (size_t)qi * HSZ + 32 + g * 8]);

    const int srow = t >> 3;
    const int schk = ((t & 7) ^ (srow & 7)) * 8;
    const u16* ksrc = kb  + base + (size_t)srow * HSZ + schk;
    const u16* vsrc = vtg + base + (size_t)srow * SLEN + schk;
    const int ldst = wid * 8 * 64;

    f32x4_t o[4] = {};
    float lrow = 0.f;

    const int ntiles = 2 * qt + 2;
    const int qw0 = q0 + wid * 16;
    const int qmax_wave = qw0 + 15;

    gld16(&Ks[0][0][0] + ldst, ksrc);
    gld16(&Vt[0][0][0] + ldst, vsrc);
    VMW0();
    __builtin_amdgcn_s_barrier();

#pragma unroll 1
    for (int kt = 0; kt < ntiles; ++kt) {
        const int kv0  = kt * 64;
        const int bsel = kt & 1;
        if (kt + 1 < ntiles) {
            gld16(&Ks[bsel ^ 1][0][0] + ldst, ksrc + (size_t)(kv0 + 64) * HSZ);
            gld16(&Vt[bsel ^ 1][0][0] + ldst, vsrc + (kv0 + 64));
        }

        if (kv0 <= qmax_wave) {
            const u16* Kb = &Ks[bsel][0][0];
            const u16* Vb = &Vt[bsel][0][0];

            f32x4_t c_[4];
            __builtin_amdgcn_s_setprio(1);
#pragma unroll
            for (int m = 0; m < 4; ++m) {
                bf16x8_t a0 = *reinterpret_cast<const bf16x8_t*>(
                    Kb + (m * 16 + r16) * 64 + (g ^ r8) * 8);
                bf16x8_t a1 = *reinterpret_cast<const bf16x8_t*>(
                    Kb + (m * 16 + r16) * 64 + ((4 + g) ^ r8) * 8);
                f32x4_t cc = {};
                cc = __builtin_amdgcn_mfma_f32_16x16x32_bf16(a0, qf0, cc, 0, 0, 0);
                cc = __builtin_amdgcn_mfma_f32_16x16x32_bf16(a1, qf1, cc, 0, 0, 0);
                c_[m] = cc;
            }
            __builtin_amdgcn_s_setprio(0);

            float p[16];
            if (kv0 + 63 > qw0) {
#pragma unroll
                for (int m = 0; m < 4; ++m)
#pragma unroll
                    for (int r = 0; r < 4; ++r) {
                        int kj = kv0 + m * 16 + g * 4 + r;
                        float sv = (kj <= qi) ? c_[m][r] : -1e30f;
                        p[m * 4 + r] = exp2_fast(sv - 4.0f);
                    }
            } else {
#pragma unroll
                for (int m = 0; m < 4; ++m)
#pragma unroll
                    for (int r = 0; r < 4; ++r)
                        p[m * 4 + r] = exp2_fast(c_[m][r] - 4.0f);
            }
            float y0 = (p[0] + p[1]) + (p[2] + p[3]);
            float y1 = (p[4] + p[5]) + (p[6] + p[7]);
            float y2 = (p[8] + p[9]) + (p[10] + p[11]);
            float y3 = (p[12] + p[13]) + (p[14] + p[15]);
            float tsum = (y0 + y1) + (y2 + y3);
            tsum += __shfl_xor(tsum, 16);
            tsum += __shfl_xor(tsum, 32);
            lrow += tsum;

#pragma unroll
            for (int m = 0; m < 4; ++m) {
                uint2 pk;
                pk.x = cvt_pk_bf16(p[m * 4 + 0], p[m * 4 + 1]);
                pk.y = cvt_pk_bf16(p[m * 4 + 2], p[m * 4 + 3]);
                *reinterpret_cast<uint2*>(&P2[wid][r16][m * 16 + g * 4]) = pk;
            }

            __builtin_amdgcn_s_setprio(1);
#pragma unroll
            for (int c = 0; c < 2; ++c) {
                bf16x8_t pf = *reinterpret_cast<const bf16x8_t*>(
                    &P2[wid][r16][c * 32 + g * 8]);
#pragma unroll
                for (int j2 = 0; j2 < 4; ++j2) {
                    bf16x8_t vf = *reinterpret_cast<const bf16x8_t*>(
                        Vb + (j2 * 16 + r16) * 64 + ((c * 4 + g) ^ r8) * 8);
                    o[j2] = __builtin_amdgcn_mfma_f32_16x16x32_bf16(
                        vf, pf, o[j2], 0, 0, 0);
                }
            }
            __builtin_amdgcn_s_setprio(0);
        }

        VMW0();
        __builtin_amdgcn_s_barrier();
    }

    float rinv = 1.0f / lrow;
    const int b = bh >> 4, h = bh & 15;
    float* outb = out + (size_t)b * (SLEN * EMB) + (size_t)h * (HSZ * SLEN);
#pragma unroll
    for (int j2 = 0; j2 < 4; ++j2) {
#pragma unroll
        for (int r = 0; r < 4; ++r) {
            int d = j2 * 16 + g * 4 + r;
            outb[(size_t)d * SLEN + qi] = o[j2][r] * rinv;
        }
    }
}

// ---------------------------------------------------------------------------
extern "C" void kernel_launch(void* const* d_in, const int* in_sizes, int n_in,
                              void* d_out, int out_size, void* d_ws, size_t ws_size,
                              hipStream_t stream) {
    const float* x  = (const float*)d_in[0];
    const float* Wq = (const float*)d_in[1];
    const float* bq = (const float*)d_in[2];
    const float* Wk = (const float*)d_in[3];
    const float* bk = (const float*)d_in[4];
    const float* Wv = (const float*)d_in[5];
    const float* bv = (const float*)d_in[6];
    float* out = (float*)d_out;

    const size_t per = (size_t)BSZ * HNO * SLEN * HSZ;   // 8,388,608
    u16* qw = (u16*)d_ws;            // q, k in [b,h,s,d]; v^T in [b,h,d,s]
    u16* kw = qw + per;
    u16* vw = kw + per;

    // bf16 scratch lives in d_out (23.1 MB < 33.5 MB); the GEMM finishes
    // reading it before attn_kernel overwrites d_out (stream-ordered).
    u16* xb = (u16*)d_out;                       // 16.8 MB
    u16* wb = xb + (size_t)BSZ * SLEN * DIN;     // 6.3 MB (Wq,Wk,Wv contiguous)

    cvt_bf16_kernel<<<dim3(256, 4), 256, 0, stream>>>(x, Wq, Wk, Wv, xb, wb);
    qkv_gemm_kernel<<<768, 256, 0, stream>>>(xb, wb, bq, bk, bv, qw, vw);
    attn_kernel<<<1024, 512, 0, stream>>>(qw, kw, vw, out);
}

// Round 11
// 118.961 us; speedup vs baseline: 1.0274x; 1.0274x over previous
//
#include <hip/hip_runtime.h>

// MHA forward, MI355X gfx950.
// Sizes: B=4, S=2048, DIN=EMB=1024, H=16, D(head)=64.
// Stage 0: one-shot fp32->bf16 convert of x and Wq/Wk/Wv.
// Stage 1: fused QKV GEMM (128x128, BK=64, 4 waves 64x64, 32 KB LDS,
//          ~3 blocks/CU). T14 loop: read frags -> regs, barrier, stage(t+1)
//          into SAME buffer under the 32-MFMA cluster, vmcnt(0), barrier.
//          XOR-chunk swizzle, LDS-bounce epilogue, V stored [b,h,d,s].
// Stage 2: causal flash attention, BQ=128 (8 waves), KVBLK=64, fixed-max
//          exp2 softmax, K/V^T gld16 dbuf, one barrier/tile (unchanged R9).

#define BSZ 4
#define SLEN 2048
#define DIN 1024
#define EMB 1024
#define HNO 16
#define HSZ 64

typedef unsigned short u16;
typedef __bf16 bf16x8_t __attribute__((ext_vector_type(8)));
typedef float f32x4_t __attribute__((ext_vector_type(4)));

__device__ __forceinline__ u16 f2bf(float f) {
    unsigned u = __float_as_uint(f);
    u += 0x7FFFu + ((u >> 16) & 1u);   // RNE; inputs are finite
    return (u16)(u >> 16);
}

__device__ __forceinline__ float exp2_fast(float x) {
    float r;
    asm("v_exp_f32 %0, %1" : "=v"(r) : "v"(x));
    return r;
}

__device__ __forceinline__ unsigned cvt_pk_bf16(float lo, float hi) {
    unsigned r;
    asm("v_cvt_pk_bf16_f32 %0, %1, %2" : "=v"(r) : "v"(lo), "v"(hi));
    return r;
}

__device__ __forceinline__ void gld16(void* lds, const void* g) {
    __builtin_amdgcn_global_load_lds(
        (const __attribute__((address_space(1))) void*)g,
        (__attribute__((address_space(3))) void*)lds, 16, 0, 0);
}

#define VMW0()                                                                 \
    do {                                                                       \
        asm volatile("s_waitcnt vmcnt(0)" ::: "memory");                       \
        __builtin_amdgcn_sched_barrier(0);                                     \
    } while (0)

#define LGKM0()                                                                \
    do {                                                                       \
        asm volatile("s_waitcnt lgkmcnt(0)" ::: "memory");                     \
        __builtin_amdgcn_sched_barrier(0);                                     \
    } while (0)

// ---------------------------------------------------------------------------
// Stage 0: fp32 -> bf16
// ---------------------------------------------------------------------------
__global__ __launch_bounds__(256) void cvt_bf16_kernel(
    const float* __restrict__ x,  const float* __restrict__ wq,
    const float* __restrict__ wk, const float* __restrict__ wv,
    u16* __restrict__ xo, u16* __restrict__ wo)
{
    const int y = blockIdx.y;
    const float* src = (y == 0) ? x : (y == 1) ? wq : (y == 2) ? wk : wv;
    u16* dst = (y == 0) ? xo : wo + (size_t)(y - 1) * (EMB * DIN);
    const int n8 = (y == 0) ? (BSZ * SLEN * DIN / 8) : (EMB * DIN / 8);

    for (int i = blockIdx.x * 256 + threadIdx.x; i < n8; i += gridDim.x * 256) {
        float4 a = *reinterpret_cast<const float4*>(src + (size_t)i * 8);
        float4 b = *reinterpret_cast<const float4*>(src + (size_t)i * 8 + 4);
        union { u16 h[8]; uint4 u; } p;
        p.h[0] = f2bf(a.x); p.h[1] = f2bf(a.y); p.h[2] = f2bf(a.z); p.h[3] = f2bf(a.w);
        p.h[4] = f2bf(b.x); p.h[5] = f2bf(b.y); p.h[6] = f2bf(b.z); p.h[7] = f2bf(b.w);
        *reinterpret_cast<uint4*>(dst + (size_t)i * 8) = p.u;
    }
}

// ---------------------------------------------------------------------------
// Stage 1: fused QKV GEMM. 128x128 tile, BK=64, 4 waves (2x2, wave 64x64).
// 32 KB LDS, T14 stage-under-MFMA loop.
// grid = 1536 (64 M x 24 N, XCD-swizzled), block = 256.
// ---------------------------------------------------------------------------
__global__ __launch_bounds__(256, 3) void qkv_gemm_kernel(
    const u16* __restrict__ xb, const u16* __restrict__ wb,
    const float* __restrict__ bq, const float* __restrict__ bk,
    const float* __restrict__ bv,
    u16* __restrict__ qkv, u16* __restrict__ vt)
{
    __shared__ __attribute__((aligned(16))) u16 SH[2 * 128 * 64];
    u16* AsF = SH;
    u16* BsF = SH + 128 * 64;

    const int t    = threadIdx.x;
    const int wid  = t >> 6;
    const int lane = t & 63;
    const int g    = lane >> 4;
    const int r16  = lane & 15;
    const int wm   = wid >> 1, wn = wid & 1;

    const int wg = blockIdx.x;
    const int x  = wg & 7;
    const int j  = wg >> 3;
    const int bx  = (x & 3) * 16 + (j & 15);
    const int byn = (x >> 2) * 12 + (j >> 4);
    const int m0  = bx * 128;
    const int n0g = byn * 128;

    const int rowoff = t >> 3;
    const int colswz = ((t & 7) ^ (rowoff & 7)) * 8;
    const u16* srcA = xb + (size_t)(m0 + rowoff) * DIN + colswz;
    const u16* srcB = wb + (size_t)(n0g + rowoff) * DIN + colswz;

    const int s0 = (g ^ (r16 & 7)) * 8;

    f32x4_t acc[4][4] = {};

    // ---- prologue: stage tile 0
#pragma unroll
    for (int u = 0; u < 4; ++u) {
        gld16(AsF + u * 2048 + t * 8, srcA + (size_t)u * 32 * DIN);
        gld16(BsF + u * 2048 + t * 8, srcB + (size_t)u * 32 * DIN);
    }
    VMW0();
    __builtin_amdgcn_s_barrier();

#pragma unroll 1
    for (int kt = 0; kt < 16; ++kt) {
        // 1. read ALL fragments of this tile into registers
        bf16x8_t af[4][2], bfv[4][2];
#pragma unroll
        for (int i2 = 0; i2 < 4; ++i2) {
            af[i2][0] = *reinterpret_cast<const bf16x8_t*>(
                AsF + (wm * 64 + i2 * 16 + r16) * 64 + s0);
            af[i2][1] = *reinterpret_cast<const bf16x8_t*>(
                AsF + (wm * 64 + i2 * 16 + r16) * 64 + (s0 ^ 32));
            bfv[i2][0] = *reinterpret_cast<const bf16x8_t*>(
                BsF + (wn * 64 + i2 * 16 + r16) * 64 + s0);
            bfv[i2][1] = *reinterpret_cast<const bf16x8_t*>(
                BsF + (wn * 64 + i2 * 16 + r16) * 64 + (s0 ^ 32));
        }
        // 2. frags in regs; all waves done reading LDS
        LGKM0();
        __builtin_amdgcn_s_barrier();
        __builtin_amdgcn_sched_barrier(0);

        // 3. stage tile t+1 into the SAME buffer (covered by MFMA below)
        if (kt != 15) {
#pragma unroll
            for (int u = 0; u < 4; ++u) {
                gld16(AsF + u * 2048 + t * 8,
                      srcA + (size_t)u * 32 * DIN + (kt + 1) * 64);
                gld16(BsF + u * 2048 + t * 8,
                      srcB + (size_t)u * 32 * DIN + (kt + 1) * 64);
            }
        }
        __builtin_amdgcn_sched_barrier(0);

        // 4. full 32-MFMA cluster on registers
        __builtin_amdgcn_s_setprio(1);
#pragma unroll
        for (int kk = 0; kk < 2; ++kk)
#pragma unroll
            for (int i2 = 0; i2 < 4; ++i2)
#pragma unroll
                for (int j2 = 0; j2 < 4; ++j2)
                    acc[i2][j2] = __builtin_amdgcn_mfma_f32_16x16x32_bf16(
                        af[i2][kk], bfv[j2][kk], acc[i2][j2], 0, 0, 0);
        __builtin_amdgcn_s_setprio(0);
        __builtin_amdgcn_sched_barrier(0);

        // 5. next tile staged & visible
        VMW0();
        __builtin_amdgcn_s_barrier();
    }

    // ---- epilogue via LDS bounce. Q/K: [b,h,s,d]; V: transposed [b,h,d,s].
    const size_t per = (size_t)BSZ * HNO * SLEN * HSZ;
    const bool isV = (n0g >= 2 * 1024);
    u16* lout = SH;
    const int b  = m0 >> 11;
    const int sB = m0 & 2047;
#pragma unroll
    for (int h = 0; h < 2; ++h) {
        __syncthreads();
        if (!isV) {
            if (wm == h) {
#pragma unroll
                for (int j2 = 0; j2 < 4; ++j2) {
                    const int el  = wn * 64 + j2 * 16 + r16;
                    const int egl = n0g + el;
                    const int mat = egl >> 10;
                    const int e   = egl & 1023;
                    const float bval = (mat == 0) ? bq[e] : bk[e];
                    const float qsv  = (mat == 0) ? 0.125f * 1.44269504f : 1.0f;
#pragma unroll
                    for (int i2 = 0; i2 < 4; ++i2)
#pragma unroll
                        for (int r = 0; r < 4; ++r) {
                            int ml = i2 * 16 + g * 4 + r;
                            lout[ml * 136 + el] =
                                f2bf((acc[i2][j2][r] + bval) * qsv);
                        }
                }
            }
            __syncthreads();
#pragma unroll
            for (int it = 0; it < 4; ++it) {
                int cid = it * 256 + t;
                int row = cid >> 4;
                int cc  = cid & 15;
                int egl = n0g + cc * 8;
                int mat = egl >> 10;
                int e   = egl & 1023;
                int s   = sB + h * 64 + row;
                uint4 v = *reinterpret_cast<const uint4*>(&lout[row * 136 + cc * 8]);
                *reinterpret_cast<uint4*>(qkv + (size_t)mat * per +
                    ((((size_t)b * HNO) + (e >> 6)) * SLEN + s) * HSZ + (e & 63)) = v;
            }
        } else {
            if (wm == h) {
#pragma unroll
                for (int j2 = 0; j2 < 4; ++j2) {
                    const int el  = wn * 64 + j2 * 16 + r16;
                    const int e   = (n0g + el) & 1023;
                    const float bval = bv[e];
#pragma unroll
                    for (int i2 = 0; i2 < 4; ++i2)
#pragma unroll
                        for (int r = 0; r < 4; ++r) {
                            int ml = i2 * 16 + g * 4 + r;
                            lout[el * 66 + ml] = f2bf(acc[i2][j2][r] + bval);
                        }
                }
            }
            __syncthreads();
#pragma unroll
            for (int it = 0; it < 4; ++it) {
                int cid  = it * 256 + t;
                int el   = cid >> 3;
                int sgrp = (cid & 7) * 8;
                int egl  = n0g + el;
                int hh   = (egl >> 6) & 15;
                int d    = egl & 63;
                int s    = sB + h * 64 + sgrp;
                uint4 v = *reinterpret_cast<const uint4*>(&lout[el * 66 + sgrp]);
                *reinterpret_cast<uint4*>(vt +
                    (((size_t)(b * HNO + hh)) * HSZ + d) * SLEN + s) = v;
            }
        }
    }
}

// ---------------------------------------------------------------------------
// Stage 2: causal flash attention (unchanged from R9).
// ---------------------------------------------------------------------------
__global__ __launch_bounds__(512, 6) void attn_kernel(
    const u16* __restrict__ qb, const u16* __restrict__ kb,
    const u16* __restrict__ vtg, float* __restrict__ out)
{
    __shared__ __attribute__((aligned(16))) u16 Ks[2][64][64];
    __shared__ __attribute__((aligned(16))) u16 Vt[2][64][64];
    __shared__ __attribute__((aligned(16))) u16 P2[8][16][72];

    const int t    = threadIdx.x;
    const int wid  = t >> 6;
    const int lane = t & 63;
    const int g    = lane >> 4;
    const int r16  = lane & 15;
    const int r8   = r16 & 7;

    const int w   = blockIdx.x;
    const int idx = w >> 3;
    const int bh  = (w & 7) * 8 + (idx & 7);
    const int qt  = 15 - (idx >> 3);
    const int q0  = qt * 128;
    const size_t base = (size_t)bh * (SLEN * HSZ);

    const int qi = q0 + wid * 16 + r16;
    bf16x8_t qf0 = *reinterpret_cast<const bf16x8_t*>(&qb[base + (size_t)qi * HSZ + g * 8]);
    bf16x8_t qf1 = *reinterpret_cast<const bf16x8_t*>(&qb[base + (size_t)qi * HSZ + 32 + g * 8]);

    const int srow = t >> 3;
    const int schk = ((t & 7) ^ (srow & 7)) * 8;
    const u16* ksrc = kb  + base + (size_t)srow * HSZ + schk;
    const u16* vsrc = vtg + base + (size_t)srow * SLEN + schk;
    const int ldst = wid * 8 * 64;

    f32x4_t o[4] = {};
    float lrow = 0.f;

    const int ntiles = 2 * qt + 2;
    const int qw0 = q0 + wid * 16;
    const int qmax_wave = qw0 + 15;

    gld16(&Ks[0][0][0] + ldst, ksrc);
    gld16(&Vt[0][0][0] + ldst, vsrc);
    VMW0();
    __builtin_amdgcn_s_barrier();

#pragma unroll 1
    for (int kt = 0; kt < ntiles; ++kt) {
        const int kv0  = kt * 64;
        const int bsel = kt & 1;
        if (kt + 1 < ntiles) {
            gld16(&Ks[bsel ^ 1][0][0] + ldst, ksrc + (size_t)(kv0 + 64) * HSZ);
            gld16(&Vt[bsel ^ 1][0][0] + ldst, vsrc + (kv0 + 64));
        }

        if (kv0 <= qmax_wave) {
            const u16* Kb = &Ks[bsel][0][0];
            const u16* Vb = &Vt[bsel][0][0];

            f32x4_t c_[4];
            __builtin_amdgcn_s_setprio(1);
#pragma unroll
            for (int m = 0; m < 4; ++m) {
                bf16x8_t a0 = *reinterpret_cast<const bf16x8_t*>(
                    Kb + (m * 16 + r16) * 64 + (g ^ r8) * 8);
                bf16x8_t a1 = *reinterpret_cast<const bf16x8_t*>(
                    Kb + (m * 16 + r16) * 64 + ((4 + g) ^ r8) * 8);
                f32x4_t cc = {};
                cc = __builtin_amdgcn_mfma_f32_16x16x32_bf16(a0, qf0, cc, 0, 0, 0);
                cc = __builtin_amdgcn_mfma_f32_16x16x32_bf16(a1, qf1, cc, 0, 0, 0);
                c_[m] = cc;
            }
            __builtin_amdgcn_s_setprio(0);

            float p[16];
            if (kv0 + 63 > qw0) {
#pragma unroll
                for (int m = 0; m < 4; ++m)
#pragma unroll
                    for (int r = 0; r < 4; ++r) {
                        int kj = kv0 + m * 16 + g * 4 + r;
                        float sv = (kj <= qi) ? c_[m][r] : -1e30f;
                        p[m * 4 + r] = exp2_fast(sv - 4.0f);
                    }
            } else {
#pragma unroll
                for (int m = 0; m < 4; ++m)
#pragma unroll
                    for (int r = 0; r < 4; ++r)
                        p[m * 4 + r] = exp2_fast(c_[m][r] - 4.0f);
            }
            float y0 = (p[0] + p[1]) + (p[2] + p[3]);
            float y1 = (p[4] + p[5]) + (p[6] + p[7]);
            float y2 = (p[8] + p[9]) + (p[10] + p[11]);
            float y3 = (p[12] + p[13]) + (p[14] + p[15]);
            float tsum = (y0 + y1) + (y2 + y3);
            tsum += __shfl_xor(tsum, 16);
            tsum += __shfl_xor(tsum, 32);
            lrow += tsum;

#pragma unroll
            for (int m = 0; m < 4; ++m) {
                uint2 pk;
                pk.x = cvt_pk_bf16(p[m * 4 + 0], p[m * 4 + 1]);
                pk.y = cvt_pk_bf16(p[m * 4 + 2], p[m * 4 + 3]);
                *reinterpret_cast<uint2*>(&P2[wid][r16][m * 16 + g * 4]) = pk;
            }

            __builtin_amdgcn_s_setprio(1);
#pragma unroll
            for (int c = 0; c < 2; ++c) {
                bf16x8_t pf = *reinterpret_cast<const bf16x8_t*>(
                    &P2[wid][r16][c * 32 + g * 8]);
#pragma unroll
                for (int j2 = 0; j2 < 4; ++j2) {
                    bf16x8_t vf = *reinterpret_cast<const bf16x8_t*>(
                        Vb + (j2 * 16 + r16) * 64 + ((c * 4 + g) ^ r8) * 8);
                    o[j2] = __builtin_amdgcn_mfma_f32_16x16x32_bf16(
                        vf, pf, o[j2], 0, 0, 0);
                }
            }
            __builtin_amdgcn_s_setprio(0);
        }

        VMW0();
        __builtin_amdgcn_s_barrier();
    }

    float rinv = 1.0f / lrow;
    const int b = bh >> 4, h = bh & 15;
    float* outb = out + (size_t)b * (SLEN * EMB) + (size_t)h * (HSZ * SLEN);
#pragma unroll
    for (int j2 = 0; j2 < 4; ++j2) {
#pragma unroll
        for (int r = 0; r < 4; ++r) {
            int d = j2 * 16 + g * 4 + r;
            outb[(size_t)d * SLEN + qi] = o[j2][r] * rinv;
        }
    }
}

// ---------------------------------------------------------------------------
extern "C" void kernel_launch(void* const* d_in, const int* in_sizes, int n_in,
                              void* d_out, int out_size, void* d_ws, size_t ws_size,
                              hipStream_t stream) {
    const float* x  = (const float*)d_in[0];
    const float* Wq = (const float*)d_in[1];
    const float* bq = (const float*)d_in[2];
    const float* Wk = (const float*)d_in[3];
    const float* bk = (const float*)d_in[4];
    const float* Wv = (const float*)d_in[5];
    const float* bv = (const float*)d_in[6];
    float* out = (float*)d_out;

    const size_t per = (size_t)BSZ * HNO * SLEN * HSZ;   // 8,388,608
    u16* qw = (u16*)d_ws;            // q, k in [b,h,s,d]; v^T in [b,h,d,s]
    u16* kw = qw + per;
    u16* vw = kw + per;

    // bf16 scratch lives in d_out (23.1 MB < 33.5 MB); the GEMM finishes
    // reading it before attn_kernel overwrites d_out (stream-ordered).
    u16* xb = (u16*)d_out;                       // 16.8 MB
    u16* wb = xb + (size_t)BSZ * SLEN * DIN;     // 6.3 MB (Wq,Wk,Wv contiguous)

    cvt_bf16_kernel<<<dim3(256, 4), 256, 0, stream>>>(x, Wq, Wk, Wv, xb, wb);
    qkv_gemm_kernel<<<1536, 256, 0, stream>>>(xb, wb, bq, bk, bv, qw, vw);
    attn_kernel<<<1024, 512, 0, stream>>>(qw, kw, vw, out);
}